// Round 1
// baseline (1541.741 us; speedup 1.0000x reference)
//
#include <hip/hip_runtime.h>
#include <stdint.h>

#define DIM 512
#define NHEAD 16
#define HEADD 32
#define BATCH 16
#define SEQL 2304
#define XROWS (BATCH*SEQL)        // 36864
#define NROWS (XROWS + BATCH)     // 36880
#define ATT_SCALE 0.17677669529663687f

typedef __attribute__((ext_vector_type(8))) short short8;
typedef __attribute__((ext_vector_type(4))) float f32x4;

__device__ __forceinline__ float bf2f(unsigned short v) {
    union { unsigned u; float f; } t; t.u = ((unsigned)v) << 16; return t.f;
}
__device__ __forceinline__ unsigned short f2bf(float f) {
    union { float f; unsigned u; } t; t.f = f;
    unsigned r = t.u + 0x7fffu + ((t.u >> 16) & 1u);
    return (unsigned short)(r >> 16);
}
__device__ __forceinline__ void unpack8(const int4 c, float* o) {
    union { unsigned u; float f; } t;
    unsigned w0 = (unsigned)c.x, w1 = (unsigned)c.y, w2 = (unsigned)c.z, w3 = (unsigned)c.w;
    t.u = w0 << 16;         o[0] = t.f;
    t.u = w0 & 0xffff0000u; o[1] = t.f;
    t.u = w1 << 16;         o[2] = t.f;
    t.u = w1 & 0xffff0000u; o[3] = t.f;
    t.u = w2 << 16;         o[4] = t.f;
    t.u = w2 & 0xffff0000u; o[5] = t.f;
    t.u = w3 << 16;         o[6] = t.f;
    t.u = w3 & 0xffff0000u; o[7] = t.f;
}

// ---------------- pack kernel: weight transposes (bf16), bias concat, rel-bias expand ----
__global__ void pack_kernel(const float* __restrict__ w_q, const float* __restrict__ w_kv,
                            const float* __restrict__ b_q, const float* __restrict__ b_kv,
                            const float* __restrict__ w_fc1, const float* __restrict__ w_fc2,
                            const float* __restrict__ rel_table,
                            unsigned short* __restrict__ Wqkv_t, unsigned short* __restrict__ Wfc1_t,
                            unsigned short* __restrict__ Wfc2_t, float* __restrict__ bqkv,
                            float* __restrict__ bias_exp) {
    int i = blockIdx.x * 256 + threadIdx.x;
    if (i < 1536*512) {                       // Wqkv_t[n][k], n in [0,1536)
        int n = i >> 9, k = i & 511;
        float v = (n < 512) ? w_q[k*512 + n] : w_kv[k*1024 + (n - 512)];
        Wqkv_t[i] = f2bf(v);
        return;
    }
    i -= 1536*512;
    if (i < 2048*512) {                       // Wfc1_t[n][k]
        int n = i >> 9, k = i & 511;
        Wfc1_t[i] = f2bf(w_fc1[k*2048 + n]);
        return;
    }
    i -= 2048*512;
    if (i < 512*2048) {                       // Wfc2_t[n][k], k in [0,2048)
        int n = i >> 11, k = i & 2047;
        Wfc2_t[i] = f2bf(w_fc2[k*512 + n]);
        return;
    }
    i -= 512*2048;
    if (i < 1536) { bqkv[i] = (i < 512) ? b_q[i] : b_kv[i - 512]; return; }
    i -= 1536;
    if (i < NHEAD*36*37) {                    // bias_exp[h][qi][j]
        int h = i / (36*37); int rem = i % (36*37); int qi = rem / 37; int j = rem % 37;
        int c0m = qi % 6, c1m = qi / 6;
        int c0n = (j < 36) ? (j % 6) : 0;
        int c1n = (j < 36) ? (j / 6) : 0;
        int id = (c0m - c0n + 5) * 11 + (c1m - c1n + 5);
        bias_exp[i] = rel_table[id * NHEAD + h];
    }
}

// ---------------- LayerNorm: one wave per 512-elem row, bf16 output ---------------------
__global__ __launch_bounds__(256) void ln_kernel(const float* __restrict__ p1,
                                                 const float* __restrict__ p2, int split,
                                                 const float* __restrict__ g, const float* __restrict__ be,
                                                 unsigned short* __restrict__ out, int nrows) {
    int wv = threadIdx.x >> 6, lane = threadIdx.x & 63;
    int r = blockIdx.x * 4 + wv;
    if (r >= nrows) return;
    const float* src = (r < split) ? (p1 + (long)r * DIM) : (p2 + (long)(r - split) * DIM);
    int c0 = lane * 8;
    float4 v0 = *(const float4*)(src + c0);
    float4 v1 = *(const float4*)(src + c0 + 4);
    float s = v0.x+v0.y+v0.z+v0.w + v1.x+v1.y+v1.z+v1.w;
    float q = v0.x*v0.x+v0.y*v0.y+v0.z*v0.z+v0.w*v0.w + v1.x*v1.x+v1.y*v1.y+v1.z*v1.z+v1.w*v1.w;
    for (int m = 1; m < 64; m <<= 1) { s += __shfl_xor(s, m); q += __shfl_xor(q, m); }
    float mean = s * (1.0f/512.0f);
    float var  = q * (1.0f/512.0f) - mean*mean;
    float rs = rsqrtf(var + 1e-3f);
    float4 g0 = *(const float4*)(g + c0);
    float4 g1 = *(const float4*)(g + c0 + 4);
    float4 b0 = *(const float4*)(be + c0);
    float4 b1 = *(const float4*)(be + c0 + 4);
    unsigned short o[8];
    o[0] = f2bf((v0.x-mean)*rs*g0.x + b0.x);
    o[1] = f2bf((v0.y-mean)*rs*g0.y + b0.y);
    o[2] = f2bf((v0.z-mean)*rs*g0.z + b0.z);
    o[3] = f2bf((v0.w-mean)*rs*g0.w + b0.w);
    o[4] = f2bf((v1.x-mean)*rs*g1.x + b1.x);
    o[5] = f2bf((v1.y-mean)*rs*g1.y + b1.y);
    o[6] = f2bf((v1.z-mean)*rs*g1.z + b1.z);
    o[7] = f2bf((v1.w-mean)*rs*g1.w + b1.w);
    *(int4*)(out + (long)r * DIM + c0) = *(const int4*)o;
}

// ---------------- bf16 MFMA GEMM: C[M][N] = A[M][K] * Bt[N][K]^T (+bias, opt GELU/res) --
template<bool GELU_ACT, bool OUT_BF16, bool HAS_RES>
__global__ __launch_bounds__(256) void gemm_kernel(const short* __restrict__ A,
                                                   const short* __restrict__ Bt,
                                                   const float* __restrict__ bias,
                                                   void* __restrict__ Cout,
                                                   const float* __restrict__ Res,
                                                   int M, int N, int K) {
    __shared__ short lds_a[128 * 40];
    __shared__ short lds_b[128 * 40];
    const int tid = threadIdx.x;
    const int lane = tid & 63;
    const int wv = tid >> 6;
    const int m0 = blockIdx.y * 128;
    const int n0 = blockIdx.x * 128;
    const int wm = (wv >> 1) * 64;
    const int wn = (wv & 1) * 64;

    f32x4 acc[4][4];
    #pragma unroll
    for (int i = 0; i < 4; i++)
        #pragma unroll
        for (int j = 0; j < 4; j++) { acc[i][j][0]=0.f; acc[i][j][1]=0.f; acc[i][j][2]=0.f; acc[i][j][3]=0.f; }

    const int srow = tid >> 1;
    const int skoff = (tid & 1) * 16;
    const int arow = m0 + srow;
    const bool avalid = arow < M;
    const long abase = (long)arow * K + skoff;
    const long bbase = (long)(n0 + srow) * K + skoff;
    short* la = &lds_a[srow * 40 + skoff];
    short* lb = &lds_b[srow * 40 + skoff];

    const int quad = lane >> 4;
    const int l15 = lane & 15;
    const short* ra = &lds_a[(wm + l15) * 40 + quad * 8];
    const short* rb = &lds_b[(wn + l15) * 40 + quad * 8];

    for (int k0 = 0; k0 < K; k0 += 32) {
        int4 a0, a1, b0, b1;
        if (avalid) {
            const int4* ap = (const int4*)(A + abase + k0);
            a0 = ap[0]; a1 = ap[1];
        } else { a0 = make_int4(0,0,0,0); a1 = a0; }
        const int4* bp = (const int4*)(Bt + bbase + k0);
        b0 = bp[0]; b1 = bp[1];
        __syncthreads();
        ((int4*)la)[0] = a0; *((int4*)(la + 8)) = a1;
        ((int4*)lb)[0] = b0; *((int4*)(lb + 8)) = b1;
        __syncthreads();
        short8 af[4], bf[4];
        #pragma unroll
        for (int mt = 0; mt < 4; mt++) af[mt] = *(const short8*)(ra + mt * 16 * 40);
        #pragma unroll
        for (int nt = 0; nt < 4; nt++) bf[nt] = *(const short8*)(rb + nt * 16 * 40);
        #pragma unroll
        for (int mt = 0; mt < 4; mt++)
            #pragma unroll
            for (int nt = 0; nt < 4; nt++)
                acc[mt][nt] = __builtin_amdgcn_mfma_f32_16x16x32_bf16(af[mt], bf[nt], acc[mt][nt], 0, 0, 0);
    }

    #pragma unroll
    for (int mt = 0; mt < 4; mt++) {
        int rbase = m0 + wm + mt * 16 + quad * 4;
        #pragma unroll
        for (int nt = 0; nt < 4; nt++) {
            int col = n0 + wn + nt * 16 + l15;
            float bv = bias[col];
            #pragma unroll
            for (int r = 0; r < 4; r++) {
                int row = rbase + r;
                if (row < M) {
                    float v = acc[mt][nt][r] + bv;
                    if (GELU_ACT) v = 0.5f * v * (1.0f + erff(v * 0.70710678118654752f));
                    if (HAS_RES) v += Res[(long)row * N + col];
                    if (OUT_BF16) ((unsigned short*)Cout)[(long)row * N + col] = f2bf(v);
                    else          ((float*)Cout)[(long)row * N + col] = v;
                }
            }
        }
    }
}

// ---------------- windowed attention: 1 block (1024 thr) per window, wave = head --------
__global__ __launch_bounds__(1024) void winattn_kernel(const short* __restrict__ qkv,
                                                       const float* __restrict__ bias_exp,
                                                       const float* __restrict__ xin,
                                                       float* __restrict__ XALL) {
    __shared__ short kv_s[37 * 512];
    const int win = blockIdx.x;
    const int b = win >> 6;
    const int i1 = (win >> 3) & 7;
    const int i3 = win & 7;
    const int tid = threadIdx.x;
    const int h = tid >> 6;
    const int lane = tid & 63;
    const int qi = lane;

    // stage K (window tokens + global token at row 36)
    for (int c = tid; c < 37 * 64; c += 1024) {
        int row = c >> 6;
        int co = (c & 63) * 8;
        int grow;
        if (row < 36) { int i2 = row / 6, i4 = row % 6; grow = b * SEQL + (i1*6 + i2) * 48 + i3*6 + i4; }
        else grow = XROWS + b;
        *(int4*)&kv_s[row * 512 + co] = *(const int4*)(qkv + (long)grow * 1536 + 512 + co);
    }
    __syncthreads();

    float s[37];
    float inv_sum = 0.f;
    int growq = 0;
    if (qi < 36) {
        int i2 = qi / 6, i4 = qi % 6;
        growq = b * SEQL + (i1*6 + i2) * 48 + i3*6 + i4;
        float qr[32];
        const int4* qp = (const int4*)(qkv + (long)growq * 1536 + h * 32);
        unpack8(qp[0], qr); unpack8(qp[1], qr + 8); unpack8(qp[2], qr + 16); unpack8(qp[3], qr + 24);
        const float* brow = bias_exp + h * (36*37) + qi * 37;
        float mx = -1e30f;
        #pragma unroll
        for (int j = 0; j < 37; j++) {
            const int4* kp = (const int4*)&kv_s[j * 512 + h * 32];
            float kr[32];
            unpack8(kp[0], kr); unpack8(kp[1], kr + 8); unpack8(kp[2], kr + 16); unpack8(kp[3], kr + 24);
            float d0 = 0.f, d1 = 0.f, d2 = 0.f, d3 = 0.f;
            #pragma unroll
            for (int dd = 0; dd < 8; dd++) {
                d0 += qr[dd]      * kr[dd];
                d1 += qr[8 + dd]  * kr[8 + dd];
                d2 += qr[16 + dd] * kr[16 + dd];
                d3 += qr[24 + dd] * kr[24 + dd];
            }
            float sv = (d0 + d1 + d2 + d3) * ATT_SCALE + brow[j];
            s[j] = sv;
            mx = fmaxf(mx, sv);
        }
        float sum = 0.f;
        #pragma unroll
        for (int j = 0; j < 37; j++) { s[j] = expf(s[j] - mx); sum += s[j]; }
        inv_sum = 1.0f / sum;
    }
    __syncthreads();
    // stage V over K
    for (int c = tid; c < 37 * 64; c += 1024) {
        int row = c >> 6;
        int co = (c & 63) * 8;
        int grow;
        if (row < 36) { int i2 = row / 6, i4 = row % 6; grow = b * SEQL + (i1*6 + i2) * 48 + i3*6 + i4; }
        else grow = XROWS + b;
        *(int4*)&kv_s[row * 512 + co] = *(const int4*)(qkv + (long)grow * 1536 + 1024 + co);
    }
    __syncthreads();
    if (qi < 36) {
        float o[32];
        #pragma unroll
        for (int dd = 0; dd < 32; dd++) o[dd] = 0.f;
        #pragma unroll
        for (int j = 0; j < 37; j++) {
            const int4* vp = (const int4*)&kv_s[j * 512 + h * 32];
            float vr[32];
            unpack8(vp[0], vr); unpack8(vp[1], vr + 8); unpack8(vp[2], vr + 16); unpack8(vp[3], vr + 24);
            float p = s[j];
            #pragma unroll
            for (int dd = 0; dd < 32; dd++) o[dd] += p * vr[dd];
        }
        const float* xi = xin + (long)growq * DIM + h * 32;
        float* xo = XALL + (long)growq * DIM + h * 32;
        #pragma unroll
        for (int dd = 0; dd < 32; dd++) xo[dd] = xi[dd] + o[dd] * inv_sum;
    }
}

// ---------------- global-token attention: 1 block (256 thr) per (batch, head) -----------
__global__ __launch_bounds__(256) void gattn_kernel(const short* __restrict__ qkv,
                                                    const float* __restrict__ xavg,
                                                    float* __restrict__ XALL) {
    const int b = blockIdx.x >> 4;
    const int h = blockIdx.x & 15;
    const int tid = threadIdx.x;
    __shared__ float qs[32];
    __shared__ float redm[4], redsum[4];
    __shared__ float wout[4][32];
    if (tid < 32) qs[tid] = bf2f(((const unsigned short*)qkv)[(long)(XROWS + b) * 1536 + h * 32 + tid]);
    __syncthreads();
    float qr[32];
    #pragma unroll
    for (int d = 0; d < 32; d++) qr[d] = qs[d];
    float s[9];
    float mx = -1e30f;
    #pragma unroll
    for (int i = 0; i < 9; i++) {
        int t = tid + i * 256;
        const int4* kp = (const int4*)(qkv + (long)(b * SEQL + t) * 1536 + 512 + h * 32);
        float kr[32];
        unpack8(kp[0], kr); unpack8(kp[1], kr + 8); unpack8(kp[2], kr + 16); unpack8(kp[3], kr + 24);
        float d0 = 0.f, d1 = 0.f, d2 = 0.f, d3 = 0.f;
        #pragma unroll
        for (int dd = 0; dd < 8; dd++) {
            d0 += qr[dd] * kr[dd]; d1 += qr[8+dd] * kr[8+dd];
            d2 += qr[16+dd] * kr[16+dd]; d3 += qr[24+dd] * kr[24+dd];
        }
        s[i] = (d0 + d1 + d2 + d3) * ATT_SCALE;
        mx = fmaxf(mx, s[i]);
    }
    for (int m = 1; m < 64; m <<= 1) mx = fmaxf(mx, __shfl_xor(mx, m));
    if ((tid & 63) == 0) redm[tid >> 6] = mx;
    __syncthreads();
    mx = fmaxf(fmaxf(redm[0], redm[1]), fmaxf(redm[2], redm[3]));
    float sum = 0.f;
    #pragma unroll
    for (int i = 0; i < 9; i++) { s[i] = expf(s[i] - mx); sum += s[i]; }
    for (int m = 1; m < 64; m <<= 1) sum += __shfl_xor(sum, m);
    if ((tid & 63) == 0) redsum[tid >> 6] = sum;
    __syncthreads();
    sum = redsum[0] + redsum[1] + redsum[2] + redsum[3];
    float o[32];
    #pragma unroll
    for (int d = 0; d < 32; d++) o[d] = 0.f;
    #pragma unroll
    for (int i = 0; i < 9; i++) {
        int t = tid + i * 256;
        const int4* vp = (const int4*)(qkv + (long)(b * SEQL + t) * 1536 + 1024 + h * 32);
        float vr[32];
        unpack8(vp[0], vr); unpack8(vp[1], vr + 8); unpack8(vp[2], vr + 16); unpack8(vp[3], vr + 24);
        float p = s[i];
        #pragma unroll
        for (int d = 0; d < 32; d++) o[d] += p * vr[d];
    }
    for (int m = 1; m < 64; m <<= 1) {
        #pragma unroll
        for (int d = 0; d < 32; d++) o[d] += __shfl_xor(o[d], m);
    }
    if ((tid & 63) == 0) {
        #pragma unroll
        for (int d = 0; d < 32; d++) wout[tid >> 6][d] = o[d];
    }
    __syncthreads();
    if (tid < 32) {
        float t = wout[0][tid] + wout[1][tid] + wout[2][tid] + wout[3][tid];
        XALL[(long)(XROWS + b) * DIM + h * 32 + tid] = xavg[b * DIM + h * 32 + tid] + t / sum;
    }
}

// ---------------- launch --------------------------------------------------------------
extern "C" void kernel_launch(void* const* d_in, const int* in_sizes, int n_in,
                              void* d_out, int out_size, void* d_ws, size_t ws_size,
                              hipStream_t stream) {
    const float* x      = (const float*)d_in[0];
    const float* xavg   = (const float*)d_in[1];
    const float* w_kv   = (const float*)d_in[2];
    const float* b_kv   = (const float*)d_in[3];
    const float* w_q    = (const float*)d_in[4];
    const float* b_q    = (const float*)d_in[5];
    const float* rel    = (const float*)d_in[6];
    const float* g1     = (const float*)d_in[7];
    const float* be1    = (const float*)d_in[8];
    const float* g2     = (const float*)d_in[9];
    const float* be2    = (const float*)d_in[10];
    const float* w_fc1  = (const float*)d_in[11];
    const float* b_fc1  = (const float*)d_in[12];
    const float* w_fc2  = (const float*)d_in[13];
    const float* b_fc2  = (const float*)d_in[14];

    char* ws = (char*)d_ws;
    size_t off = 0;
    auto alloc = [&](size_t bytes) { void* p = ws + off; off += (bytes + 255) & ~(size_t)255; return p; };
    short* qkv_h          = (short*)alloc((size_t)NROWS * 2048 * 2);   // qkv (1536 cols), then MLP hidden (2048 cols)
    float* XALL           = (float*)alloc((size_t)NROWS * 512 * 4);    // attn + residual, f32
    short* xn             = (short*)alloc((size_t)NROWS * 512 * 2);    // LN output, bf16 (reused LN1/LN2)
    unsigned short* Wqkv_t = (unsigned short*)alloc((size_t)1536 * 512 * 2);
    unsigned short* Wfc1_t = (unsigned short*)alloc((size_t)2048 * 512 * 2);
    unsigned short* Wfc2_t = (unsigned short*)alloc((size_t)512 * 2048 * 2);
    float* bqkv           = (float*)alloc(1536 * 4);
    float* bias_exp       = (float*)alloc((size_t)NHEAD * 36 * 37 * 4);

    // 1. pack weights (transposed bf16), concat qkv bias, expand rel-pos bias
    {
        int total = 1536*512 + 2048*512 + 512*2048 + 1536 + NHEAD*36*37;
        pack_kernel<<<(total + 255) / 256, 256, 0, stream>>>(w_q, w_kv, b_q, b_kv, w_fc1, w_fc2, rel,
                                                             Wqkv_t, Wfc1_t, Wfc2_t, bqkv, bias_exp);
    }
    // 2. LN1 over x rows then xavg rows -> xn (bf16)
    ln_kernel<<<(NROWS + 3) / 4, 256, 0, stream>>>(x, xavg, XROWS, g1, be1, (unsigned short*)xn, NROWS);
    // 3. QKV GEMM: [36880,512] x [512,1536] -> qkv bf16
    gemm_kernel<false, true, false><<<dim3(1536 / 128, (NROWS + 127) / 128), 256, 0, stream>>>(
        xn, (const short*)Wqkv_t, bqkv, qkv_h, nullptr, NROWS, 1536, 512);
    // 4. windowed attention + residual -> XALL rows [0, 36864)
    winattn_kernel<<<1024, 1024, 0, stream>>>(qkv_h, bias_exp, x, XALL);
    // 5. global-token attention + residual -> XALL rows [36864, 36880)
    gattn_kernel<<<256, 256, 0, stream>>>(qkv_h, xavg, XALL);
    // 6. LN2 -> xn (bf16)
    ln_kernel<<<(NROWS + 3) / 4, 256, 0, stream>>>(XALL, XALL + (size_t)XROWS * 512, XROWS, g2, be2,
                                                   (unsigned short*)xn, NROWS);
    // 7. FC1 + GELU: [36880,512] x [512,2048] -> hidden bf16 (reuses qkv region)
    gemm_kernel<true, true, false><<<dim3(2048 / 128, (NROWS + 127) / 128), 256, 0, stream>>>(
        xn, (const short*)Wfc1_t, b_fc1, qkv_h, nullptr, NROWS, 2048, 512);
    // 8. FC2 + bias + residual: [36880,2048] x [2048,512] -> d_out f32
    gemm_kernel<false, false, true><<<dim3(512 / 128, (NROWS + 127) / 128), 256, 0, stream>>>(
        qkv_h, (const short*)Wfc2_t, b_fc2, d_out, XALL, NROWS, 512, 2048);
}

// Round 2
// 927.955 us; speedup vs baseline: 1.6614x; 1.6614x over previous
//
#include <hip/hip_runtime.h>
#include <stdint.h>

#define DIM 512
#define NHEAD 16
#define HEADD 32
#define BATCH 16
#define SEQL 2304
#define XROWS (BATCH*SEQL)        // 36864
#define NROWS (XROWS + BATCH)     // 36880
#define ATT_SCALE 0.17677669529663687f

typedef __attribute__((ext_vector_type(8))) short short8;
typedef __attribute__((ext_vector_type(4))) float f32x4;

__device__ __forceinline__ float bf2f(unsigned short v) {
    union { unsigned u; float f; } t; t.u = ((unsigned)v) << 16; return t.f;
}
__device__ __forceinline__ unsigned short f2bf(float f) {
    union { float f; unsigned u; } t; t.f = f;
    unsigned r = t.u + 0x7fffu + ((t.u >> 16) & 1u);
    return (unsigned short)(r >> 16);
}
__device__ __forceinline__ void unpack8(const int4 c, float* o) {
    union { unsigned u; float f; } t;
    unsigned w0 = (unsigned)c.x, w1 = (unsigned)c.y, w2 = (unsigned)c.z, w3 = (unsigned)c.w;
    t.u = w0 << 16;         o[0] = t.f;
    t.u = w0 & 0xffff0000u; o[1] = t.f;
    t.u = w1 << 16;         o[2] = t.f;
    t.u = w1 & 0xffff0000u; o[3] = t.f;
    t.u = w2 << 16;         o[4] = t.f;
    t.u = w2 & 0xffff0000u; o[5] = t.f;
    t.u = w3 << 16;         o[6] = t.f;
    t.u = w3 & 0xffff0000u; o[7] = t.f;
}

// ---------------- pack kernel: weight transposes (bf16), bias concat, rel-bias expand ----
__global__ void pack_kernel(const float* __restrict__ w_q, const float* __restrict__ w_kv,
                            const float* __restrict__ b_q, const float* __restrict__ b_kv,
                            const float* __restrict__ w_fc1, const float* __restrict__ w_fc2,
                            const float* __restrict__ rel_table,
                            unsigned short* __restrict__ Wqkv_t, unsigned short* __restrict__ Wfc1_t,
                            unsigned short* __restrict__ Wfc2_t, float* __restrict__ bqkv,
                            float* __restrict__ bias_exp) {
    int i = blockIdx.x * 256 + threadIdx.x;
    if (i < 1536*512) {                       // Wqkv_t[n][k], n in [0,1536)
        int n = i >> 9, k = i & 511;
        float v = (n < 512) ? w_q[k*512 + n] : w_kv[k*1024 + (n - 512)];
        Wqkv_t[i] = f2bf(v);
        return;
    }
    i -= 1536*512;
    if (i < 2048*512) {                       // Wfc1_t[n][k]
        int n = i >> 9, k = i & 511;
        Wfc1_t[i] = f2bf(w_fc1[k*2048 + n]);
        return;
    }
    i -= 2048*512;
    if (i < 512*2048) {                       // Wfc2_t[n][k], k in [0,2048)
        int n = i >> 11, k = i & 2047;
        Wfc2_t[i] = f2bf(w_fc2[k*512 + n]);
        return;
    }
    i -= 512*2048;
    if (i < 1536) { bqkv[i] = (i < 512) ? b_q[i] : b_kv[i - 512]; return; }
    i -= 1536;
    if (i < NHEAD*36*37) {                    // bias_exp[h][qi][j]
        int h = i / (36*37); int rem = i % (36*37); int qi = rem / 37; int j = rem % 37;
        int c0m = qi % 6, c1m = qi / 6;
        int c0n = (j < 36) ? (j % 6) : 0;
        int c1n = (j < 36) ? (j / 6) : 0;
        int id = (c0m - c0n + 5) * 11 + (c1m - c1n + 5);
        bias_exp[i] = rel_table[id * NHEAD + h];
    }
}

// ---------------- LayerNorm: one wave per 512-elem row, bf16 output ---------------------
__global__ __launch_bounds__(256) void ln_kernel(const float* __restrict__ p1,
                                                 const float* __restrict__ p2, int split,
                                                 const float* __restrict__ g, const float* __restrict__ be,
                                                 unsigned short* __restrict__ out, int nrows) {
    int wv = threadIdx.x >> 6, lane = threadIdx.x & 63;
    int r = blockIdx.x * 4 + wv;
    if (r >= nrows) return;
    const float* src = (r < split) ? (p1 + (long)r * DIM) : (p2 + (long)(r - split) * DIM);
    int c0 = lane * 8;
    float4 v0 = *(const float4*)(src + c0);
    float4 v1 = *(const float4*)(src + c0 + 4);
    float s = v0.x+v0.y+v0.z+v0.w + v1.x+v1.y+v1.z+v1.w;
    float q = v0.x*v0.x+v0.y*v0.y+v0.z*v0.z+v0.w*v0.w + v1.x*v1.x+v1.y*v1.y+v1.z*v1.z+v1.w*v1.w;
    for (int m = 1; m < 64; m <<= 1) { s += __shfl_xor(s, m); q += __shfl_xor(q, m); }
    float mean = s * (1.0f/512.0f);
    float var  = q * (1.0f/512.0f) - mean*mean;
    float rs = rsqrtf(var + 1e-3f);
    float4 g0 = *(const float4*)(g + c0);
    float4 g1 = *(const float4*)(g + c0 + 4);
    float4 b0 = *(const float4*)(be + c0);
    float4 b1 = *(const float4*)(be + c0 + 4);
    unsigned short o[8];
    o[0] = f2bf((v0.x-mean)*rs*g0.x + b0.x);
    o[1] = f2bf((v0.y-mean)*rs*g0.y + b0.y);
    o[2] = f2bf((v0.z-mean)*rs*g0.z + b0.z);
    o[3] = f2bf((v0.w-mean)*rs*g0.w + b0.w);
    o[4] = f2bf((v1.x-mean)*rs*g1.x + b1.x);
    o[5] = f2bf((v1.y-mean)*rs*g1.y + b1.y);
    o[6] = f2bf((v1.z-mean)*rs*g1.z + b1.z);
    o[7] = f2bf((v1.w-mean)*rs*g1.w + b1.w);
    *(int4*)(out + (long)r * DIM + c0) = *(const int4*)o;
}

// ---------------- bf16 MFMA GEMM: C[M][N] = A[M][K] * Bt[N][K]^T (+bias, opt GELU/res) --
template<bool GELU_ACT, bool OUT_BF16, bool HAS_RES>
__global__ __launch_bounds__(256) void gemm_kernel(const short* __restrict__ A,
                                                   const short* __restrict__ Bt,
                                                   const float* __restrict__ bias,
                                                   void* __restrict__ Cout,
                                                   const float* __restrict__ Res,
                                                   int M, int N, int K) {
    __shared__ short lds_a[128 * 40];
    __shared__ short lds_b[128 * 40];
    const int tid = threadIdx.x;
    const int lane = tid & 63;
    const int wv = tid >> 6;
    const int m0 = blockIdx.y * 128;
    const int n0 = blockIdx.x * 128;
    const int wm = (wv >> 1) * 64;
    const int wn = (wv & 1) * 64;

    f32x4 acc[4][4];
    #pragma unroll
    for (int i = 0; i < 4; i++)
        #pragma unroll
        for (int j = 0; j < 4; j++) { acc[i][j][0]=0.f; acc[i][j][1]=0.f; acc[i][j][2]=0.f; acc[i][j][3]=0.f; }

    const int srow = tid >> 1;
    const int skoff = (tid & 1) * 16;
    const int arow = m0 + srow;
    const bool avalid = arow < M;
    const long abase = (long)arow * K + skoff;
    const long bbase = (long)(n0 + srow) * K + skoff;
    short* la = &lds_a[srow * 40 + skoff];
    short* lb = &lds_b[srow * 40 + skoff];

    const int quad = lane >> 4;
    const int l15 = lane & 15;
    const short* ra = &lds_a[(wm + l15) * 40 + quad * 8];
    const short* rb = &lds_b[(wn + l15) * 40 + quad * 8];

    for (int k0 = 0; k0 < K; k0 += 32) {
        int4 a0, a1, b0, b1;
        if (avalid) {
            const int4* ap = (const int4*)(A + abase + k0);
            a0 = ap[0]; a1 = ap[1];
        } else { a0 = make_int4(0,0,0,0); a1 = a0; }
        const int4* bp = (const int4*)(Bt + bbase + k0);
        b0 = bp[0]; b1 = bp[1];
        __syncthreads();
        ((int4*)la)[0] = a0; *((int4*)(la + 8)) = a1;
        ((int4*)lb)[0] = b0; *((int4*)(lb + 8)) = b1;
        __syncthreads();
        short8 af[4], bf[4];
        #pragma unroll
        for (int mt = 0; mt < 4; mt++) af[mt] = *(const short8*)(ra + mt * 16 * 40);
        #pragma unroll
        for (int nt = 0; nt < 4; nt++) bf[nt] = *(const short8*)(rb + nt * 16 * 40);
        #pragma unroll
        for (int mt = 0; mt < 4; mt++)
            #pragma unroll
            for (int nt = 0; nt < 4; nt++)
                acc[mt][nt] = __builtin_amdgcn_mfma_f32_16x16x32_bf16(af[mt], bf[nt], acc[mt][nt], 0, 0, 0);
    }

    #pragma unroll
    for (int mt = 0; mt < 4; mt++) {
        int rbase = m0 + wm + mt * 16 + quad * 4;
        #pragma unroll
        for (int nt = 0; nt < 4; nt++) {
            int col = n0 + wn + nt * 16 + l15;
            float bv = bias[col];
            #pragma unroll
            for (int r = 0; r < 4; r++) {
                int row = rbase + r;
                if (row < M) {
                    float v = acc[mt][nt][r] + bv;
                    if (GELU_ACT) v = 0.5f * v * (1.0f + erff(v * 0.70710678118654752f));
                    if (HAS_RES) v += Res[(long)row * N + col];
                    if (OUT_BF16) ((unsigned short*)Cout)[(long)row * N + col] = f2bf(v);
                    else          ((float*)Cout)[(long)row * N + col] = v;
                }
            }
        }
    }
}

// ---------------- windowed attention: wave = (window, head); 256-thr blocks (no spills) --
__global__ __launch_bounds__(256) void winattn_kernel(const short* __restrict__ qkv,
                                                      const float* __restrict__ bias_exp,
                                                      const float* __restrict__ xin,
                                                      float* __restrict__ XALL) {
    // per-wave LDS: 37 rows x (32 K-shorts | 32 V-shorts)
    __shared__ short kvs[4][37 * 64];
    const int tid = threadIdx.x;
    const int wv = tid >> 6;
    const int lane = tid & 63;
    const int gw = blockIdx.x * 4 + wv;            // global wave = (win, head)
    const int win = gw >> 4;
    const int h = gw & 15;
    const int b = win >> 6;
    const int i1 = (win >> 3) & 7;
    const int i3 = win & 7;

    short* lws = kvs[wv];

    // stage this head's K and V slices: 37 rows x 64B each, exact-byte fetch
    // c in [0, 296): c<148 => K, else V; 4 int4 per row
    for (int c = lane; c < 296; c += 64) {
        int cc = c;
        int voff = 512;          // K columns
        int doff = 0;
        if (cc >= 148) { cc -= 148; voff = 1024; doff = 32; }
        int row = cc >> 2;
        int part = cc & 3;
        int grow;
        if (row < 36) { int i2 = row / 6, i4 = row % 6; grow = b * SEQL + (i1*6 + i2) * 48 + i3*6 + i4; }
        else grow = XROWS + b;
        *(int4*)&lws[row * 64 + doff + part * 8] =
            *(const int4*)(qkv + (long)grow * 1536 + voff + h * 32 + part * 8);
    }
    __syncthreads();

    const int qi = lane;
    if (qi >= 36) return;
    int i2 = qi / 6, i4 = qi % 6;
    const int growq = b * SEQL + (i1*6 + i2) * 48 + i3*6 + i4;

    // load Q row (this head), pre-scale
    float qr[32];
    {
        const int4* qp = (const int4*)(qkv + (long)growq * 1536 + h * 32);
        unpack8(qp[0], qr); unpack8(qp[1], qr + 8); unpack8(qp[2], qr + 16); unpack8(qp[3], qr + 24);
        #pragma unroll
        for (int d = 0; d < 32; d++) qr[d] *= ATT_SCALE;
    }

    const float* brow = bias_exp + h * (36*37) + qi * 37;
    float s[37];
    float mx = -1e30f;
    #pragma unroll
    for (int j = 0; j < 37; j++) {
        const int4* kp = (const int4*)&lws[j * 64];
        float kr[32];
        unpack8(kp[0], kr); unpack8(kp[1], kr + 8); unpack8(kp[2], kr + 16); unpack8(kp[3], kr + 24);
        float d0 = 0.f, d1 = 0.f, d2 = 0.f, d3 = 0.f;
        #pragma unroll
        for (int dd = 0; dd < 8; dd++) {
            d0 += qr[dd]      * kr[dd];
            d1 += qr[8 + dd]  * kr[8 + dd];
            d2 += qr[16 + dd] * kr[16 + dd];
            d3 += qr[24 + dd] * kr[24 + dd];
        }
        float sv = (d0 + d1 + d2 + d3) + brow[j];
        s[j] = sv;
        mx = fmaxf(mx, sv);
    }
    float sum = 0.f;
    #pragma unroll
    for (int j = 0; j < 37; j++) { s[j] = __expf(s[j] - mx); sum += s[j]; }
    float inv_sum = 1.0f / sum;

    float o[32];
    #pragma unroll
    for (int dd = 0; dd < 32; dd++) o[dd] = 0.f;
    #pragma unroll
    for (int j = 0; j < 37; j++) {
        const int4* vp = (const int4*)&lws[j * 64 + 32];
        float vr[32];
        unpack8(vp[0], vr); unpack8(vp[1], vr + 8); unpack8(vp[2], vr + 16); unpack8(vp[3], vr + 24);
        float p = s[j];
        #pragma unroll
        for (int dd = 0; dd < 32; dd++) o[dd] += p * vr[dd];
    }

    const float* xi = xin + (long)growq * DIM + h * 32;
    float* xo = XALL + (long)growq * DIM + h * 32;
    #pragma unroll
    for (int v4 = 0; v4 < 8; v4++) {
        float4 xv = *(const float4*)(xi + v4 * 4);
        float4 ov;
        ov.x = xv.x + o[v4*4 + 0] * inv_sum;
        ov.y = xv.y + o[v4*4 + 1] * inv_sum;
        ov.z = xv.z + o[v4*4 + 2] * inv_sum;
        ov.w = xv.w + o[v4*4 + 3] * inv_sum;
        *(float4*)(xo + v4 * 4) = ov;
    }
}

// ---------------- global-token attention: 1 block (256 thr) per (batch, head) -----------
__global__ __launch_bounds__(256) void gattn_kernel(const short* __restrict__ qkv,
                                                    const float* __restrict__ xavg,
                                                    float* __restrict__ XALL) {
    const int b = blockIdx.x >> 4;
    const int h = blockIdx.x & 15;
    const int tid = threadIdx.x;
    __shared__ float qs[32];
    __shared__ float redm[4], redsum[4];
    __shared__ float wout[4][32];
    if (tid < 32) qs[tid] = bf2f(((const unsigned short*)qkv)[(long)(XROWS + b) * 1536 + h * 32 + tid]);
    __syncthreads();
    float qr[32];
    #pragma unroll
    for (int d = 0; d < 32; d++) qr[d] = qs[d];
    float s[9];
    float mx = -1e30f;
    #pragma unroll
    for (int i = 0; i < 9; i++) {
        int t = tid + i * 256;
        const int4* kp = (const int4*)(qkv + (long)(b * SEQL + t) * 1536 + 512 + h * 32);
        float kr[32];
        unpack8(kp[0], kr); unpack8(kp[1], kr + 8); unpack8(kp[2], kr + 16); unpack8(kp[3], kr + 24);
        float d0 = 0.f, d1 = 0.f, d2 = 0.f, d3 = 0.f;
        #pragma unroll
        for (int dd = 0; dd < 8; dd++) {
            d0 += qr[dd] * kr[dd]; d1 += qr[8+dd] * kr[8+dd];
            d2 += qr[16+dd] * kr[16+dd]; d3 += qr[24+dd] * kr[24+dd];
        }
        s[i] = (d0 + d1 + d2 + d3) * ATT_SCALE;
        mx = fmaxf(mx, s[i]);
    }
    for (int m = 1; m < 64; m <<= 1) mx = fmaxf(mx, __shfl_xor(mx, m));
    if ((tid & 63) == 0) redm[tid >> 6] = mx;
    __syncthreads();
    mx = fmaxf(fmaxf(redm[0], redm[1]), fmaxf(redm[2], redm[3]));
    float sum = 0.f;
    #pragma unroll
    for (int i = 0; i < 9; i++) { s[i] = __expf(s[i] - mx); sum += s[i]; }
    for (int m = 1; m < 64; m <<= 1) sum += __shfl_xor(sum, m);
    if ((tid & 63) == 0) redsum[tid >> 6] = sum;
    __syncthreads();
    sum = redsum[0] + redsum[1] + redsum[2] + redsum[3];
    float o[32];
    #pragma unroll
    for (int d = 0; d < 32; d++) o[d] = 0.f;
    #pragma unroll
    for (int i = 0; i < 9; i++) {
        int t = tid + i * 256;
        const int4* vp = (const int4*)(qkv + (long)(b * SEQL + t) * 1536 + 1024 + h * 32);
        float vr[32];
        unpack8(vp[0], vr); unpack8(vp[1], vr + 8); unpack8(vp[2], vr + 16); unpack8(vp[3], vr + 24);
        float p = s[i];
        #pragma unroll
        for (int d = 0; d < 32; d++) o[d] += p * vr[d];
    }
    for (int m = 1; m < 64; m <<= 1) {
        #pragma unroll
        for (int d = 0; d < 32; d++) o[d] += __shfl_xor(o[d], m);
    }
    if ((tid & 63) == 0) {
        #pragma unroll
        for (int d = 0; d < 32; d++) wout[tid >> 6][d] = o[d];
    }
    __syncthreads();
    if (tid < 32) {
        float t = wout[0][tid] + wout[1][tid] + wout[2][tid] + wout[3][tid];
        XALL[(long)(XROWS + b) * DIM + h * 32 + tid] = xavg[b * DIM + h * 32 + tid] + t / sum;
    }
}

// ---------------- launch --------------------------------------------------------------
extern "C" void kernel_launch(void* const* d_in, const int* in_sizes, int n_in,
                              void* d_out, int out_size, void* d_ws, size_t ws_size,
                              hipStream_t stream) {
    const float* x      = (const float*)d_in[0];
    const float* xavg   = (const float*)d_in[1];
    const float* w_kv   = (const float*)d_in[2];
    const float* b_kv   = (const float*)d_in[3];
    const float* w_q    = (const float*)d_in[4];
    const float* b_q    = (const float*)d_in[5];
    const float* rel    = (const float*)d_in[6];
    const float* g1     = (const float*)d_in[7];
    const float* be1    = (const float*)d_in[8];
    const float* g2     = (const float*)d_in[9];
    const float* be2    = (const float*)d_in[10];
    const float* w_fc1  = (const float*)d_in[11];
    const float* b_fc1  = (const float*)d_in[12];
    const float* w_fc2  = (const float*)d_in[13];
    const float* b_fc2  = (const float*)d_in[14];

    char* ws = (char*)d_ws;
    size_t off = 0;
    auto alloc = [&](size_t bytes) { void* p = ws + off; off += (bytes + 255) & ~(size_t)255; return p; };
    short* qkv_h          = (short*)alloc((size_t)NROWS * 2048 * 2);   // qkv (1536 cols), then MLP hidden (2048 cols)
    float* XALL           = (float*)alloc((size_t)NROWS * 512 * 4);    // attn + residual, f32
    short* xn             = (short*)alloc((size_t)NROWS * 512 * 2);    // LN output, bf16 (reused LN1/LN2)
    unsigned short* Wqkv_t = (unsigned short*)alloc((size_t)1536 * 512 * 2);
    unsigned short* Wfc1_t = (unsigned short*)alloc((size_t)2048 * 512 * 2);
    unsigned short* Wfc2_t = (unsigned short*)alloc((size_t)512 * 2048 * 2);
    float* bqkv           = (float*)alloc(1536 * 4);
    float* bias_exp       = (float*)alloc((size_t)NHEAD * 36 * 37 * 4);

    // 1. pack weights (transposed bf16), concat qkv bias, expand rel-pos bias
    {
        int total = 1536*512 + 2048*512 + 512*2048 + 1536 + NHEAD*36*37;
        pack_kernel<<<(total + 255) / 256, 256, 0, stream>>>(w_q, w_kv, b_q, b_kv, w_fc1, w_fc2, rel,
                                                             Wqkv_t, Wfc1_t, Wfc2_t, bqkv, bias_exp);
    }
    // 2. LN1 over x rows then xavg rows -> xn (bf16)
    ln_kernel<<<(NROWS + 3) / 4, 256, 0, stream>>>(x, xavg, XROWS, g1, be1, (unsigned short*)xn, NROWS);
    // 3. QKV GEMM: [36880,512] x [512,1536] -> qkv bf16
    gemm_kernel<false, true, false><<<dim3(1536 / 128, (NROWS + 127) / 128), 256, 0, stream>>>(
        xn, (const short*)Wqkv_t, bqkv, qkv_h, nullptr, NROWS, 1536, 512);
    // 4. windowed attention + residual -> XALL rows [0, 36864)
    winattn_kernel<<<1024 * 16 / 4, 256, 0, stream>>>(qkv_h, bias_exp, x, XALL);
    // 5. global-token attention + residual -> XALL rows [36864, 36880)
    gattn_kernel<<<256, 256, 0, stream>>>(qkv_h, xavg, XALL);
    // 6. LN2 -> xn (bf16)
    ln_kernel<<<(NROWS + 3) / 4, 256, 0, stream>>>(XALL, XALL + (size_t)XROWS * 512, XROWS, g2, be2,
                                                   (unsigned short*)xn, NROWS);
    // 7. FC1 + GELU: [36880,512] x [512,2048] -> hidden bf16 (reuses qkv region)
    gemm_kernel<true, true, false><<<dim3(2048 / 128, (NROWS + 127) / 128), 256, 0, stream>>>(
        xn, (const short*)Wfc1_t, b_fc1, qkv_h, nullptr, NROWS, 2048, 512);
    // 8. FC2 + bias + residual: [36880,2048] x [2048,512] -> d_out f32
    gemm_kernel<false, false, true><<<dim3(512 / 128, (NROWS + 127) / 128), 256, 0, stream>>>(
        qkv_h, (const short*)Wfc2_t, b_fc2, d_out, XALL, NROWS, 512, 2048);
}

// Round 3
// 814.050 us; speedup vs baseline: 1.8939x; 1.1399x over previous
//
#include <hip/hip_runtime.h>
#include <stdint.h>

#define DIM 512
#define NHEAD 16
#define HEADD 32
#define BATCH 16
#define SEQL 2304
#define XROWS (BATCH*SEQL)        // 36864
#define NROWS (XROWS + BATCH)     // 36880
#define ATT_SCALE 0.17677669529663687f

typedef __attribute__((ext_vector_type(8))) short short8;
typedef __attribute__((ext_vector_type(4))) float f32x4;

__device__ __forceinline__ float bf2f(unsigned short v) {
    union { unsigned u; float f; } t; t.u = ((unsigned)v) << 16; return t.f;
}
__device__ __forceinline__ unsigned short f2bf(float f) {
    union { float f; unsigned u; } t; t.f = f;
    unsigned r = t.u + 0x7fffu + ((t.u >> 16) & 1u);
    return (unsigned short)(r >> 16);
}
__device__ __forceinline__ void unpack8(const int4 c, float* o) {
    union { unsigned u; float f; } t;
    unsigned w0 = (unsigned)c.x, w1 = (unsigned)c.y, w2 = (unsigned)c.z, w3 = (unsigned)c.w;
    t.u = w0 << 16;         o[0] = t.f;
    t.u = w0 & 0xffff0000u; o[1] = t.f;
    t.u = w1 << 16;         o[2] = t.f;
    t.u = w1 & 0xffff0000u; o[3] = t.f;
    t.u = w2 << 16;         o[4] = t.f;
    t.u = w2 & 0xffff0000u; o[5] = t.f;
    t.u = w3 << 16;         o[6] = t.f;
    t.u = w3 & 0xffff0000u; o[7] = t.f;
}
__device__ __forceinline__ void gl_lds16(const void* g, void* l) {
    __builtin_amdgcn_global_load_lds((const __attribute__((address_space(1))) unsigned int*)g,
                                     (__attribute__((address_space(3))) unsigned int*)l,
                                     16, 0, 0);
}

// ---------------- tiled transpose: f32 [Kd][Nd] -> bf16 [Nd][Kd], coalesced both sides --
__global__ __launch_bounds__(256) void tpose_kernel(const float* __restrict__ w_q,
                                                    const float* __restrict__ w_kv,
                                                    const float* __restrict__ w_fc1,
                                                    const float* __restrict__ w_fc2,
                                                    unsigned short* __restrict__ Wqkv_t,
                                                    unsigned short* __restrict__ Wfc1_t,
                                                    unsigned short* __restrict__ Wfc2_t) {
    __shared__ float tile[32][33];
    int t = blockIdx.x;
    const float* src; unsigned short* dst;
    int Kd, Nd, rowOff, tk;
    if (t < 256)        { src = w_q;   dst = Wqkv_t; Kd = 512;  Nd = 512;  rowOff = 0;   tk = 16; }
    else if (t < 768)   { t -= 256;  src = w_kv;  dst = Wqkv_t; Kd = 512;  Nd = 1024; rowOff = 512; tk = 16; }
    else if (t < 1792)  { t -= 768;  src = w_fc1; dst = Wfc1_t; Kd = 512;  Nd = 2048; rowOff = 0;   tk = 16; }
    else                { t -= 1792; src = w_fc2; dst = Wfc2_t; Kd = 2048; Nd = 512;  rowOff = 0;   tk = 64; }
    int k0 = (t % tk) * 32;
    int n0 = (t / tk) * 32;
    int tx = threadIdx.x & 31, ty = threadIdx.x >> 5;
    #pragma unroll
    for (int r = 0; r < 32; r += 8)
        tile[r + ty][tx] = src[(long)(k0 + r + ty) * Nd + n0 + tx];
    __syncthreads();
    #pragma unroll
    for (int r = 0; r < 32; r += 8)
        dst[(long)(rowOff + n0 + r + ty) * Kd + k0 + tx] = f2bf(tile[tx][r + ty]);
}

// ---------------- small pack: qkv bias concat + rel-bias expand -------------------------
__global__ void smallpack_kernel(const float* __restrict__ b_q, const float* __restrict__ b_kv,
                                 const float* __restrict__ rel_table,
                                 float* __restrict__ bqkv, float* __restrict__ bias_exp) {
    int i = blockIdx.x * 256 + threadIdx.x;
    if (i < 1536) { bqkv[i] = (i < 512) ? b_q[i] : b_kv[i - 512]; return; }
    i -= 1536;
    if (i < NHEAD*36*37) {                    // bias_exp[h][qi][j]
        int h = i / (36*37); int rem = i % (36*37); int qi = rem / 37; int j = rem % 37;
        int c0m = qi % 6, c1m = qi / 6;
        int c0n = (j < 36) ? (j % 6) : 0;
        int c1n = (j < 36) ? (j / 6) : 0;
        int id = (c0m - c0n + 5) * 11 + (c1m - c1n + 5);
        bias_exp[i] = rel_table[id * NHEAD + h];
    }
}

// ---------------- LayerNorm: one wave per 512-elem row, bf16 output ---------------------
__global__ __launch_bounds__(256) void ln_kernel(const float* __restrict__ p1,
                                                 const float* __restrict__ p2, int split,
                                                 const float* __restrict__ g, const float* __restrict__ be,
                                                 unsigned short* __restrict__ out, int nrows) {
    int wv = threadIdx.x >> 6, lane = threadIdx.x & 63;
    int r = blockIdx.x * 4 + wv;
    if (r >= nrows) return;
    const float* src = (r < split) ? (p1 + (long)r * DIM) : (p2 + (long)(r - split) * DIM);
    int c0 = lane * 8;
    float4 v0 = *(const float4*)(src + c0);
    float4 v1 = *(const float4*)(src + c0 + 4);
    float s = v0.x+v0.y+v0.z+v0.w + v1.x+v1.y+v1.z+v1.w;
    float q = v0.x*v0.x+v0.y*v0.y+v0.z*v0.z+v0.w*v0.w + v1.x*v1.x+v1.y*v1.y+v1.z*v1.z+v1.w*v1.w;
    for (int m = 1; m < 64; m <<= 1) { s += __shfl_xor(s, m); q += __shfl_xor(q, m); }
    float mean = s * (1.0f/512.0f);
    float var  = q * (1.0f/512.0f) - mean*mean;
    float rs = rsqrtf(var + 1e-3f);
    float4 g0 = *(const float4*)(g + c0);
    float4 g1 = *(const float4*)(g + c0 + 4);
    float4 b0 = *(const float4*)(be + c0);
    float4 b1 = *(const float4*)(be + c0 + 4);
    unsigned short o[8];
    o[0] = f2bf((v0.x-mean)*rs*g0.x + b0.x);
    o[1] = f2bf((v0.y-mean)*rs*g0.y + b0.y);
    o[2] = f2bf((v0.z-mean)*rs*g0.z + b0.z);
    o[3] = f2bf((v0.w-mean)*rs*g0.w + b0.w);
    o[4] = f2bf((v1.x-mean)*rs*g1.x + b1.x);
    o[5] = f2bf((v1.y-mean)*rs*g1.y + b1.y);
    o[6] = f2bf((v1.z-mean)*rs*g1.z + b1.z);
    o[7] = f2bf((v1.w-mean)*rs*g1.w + b1.w);
    *(int4*)(out + (long)r * DIM + c0) = *(const int4*)o;
}

// ---------------- bf16 MFMA GEMM (m97 structure): global_load_lds width-16 staging ------
// C[M][N] = A[M][K] * Bt[N][K]^T (+bias, opt GELU / residual). 128x128 tile, BK=32.
template<bool GELU_ACT, bool OUT_BF16, bool HAS_RES>
__global__ __launch_bounds__(256) void gemm_kernel(const short* __restrict__ A,
                                                   const short* __restrict__ Bt,
                                                   const float* __restrict__ bias,
                                                   void* __restrict__ Cout,
                                                   const float* __restrict__ Res,
                                                   int M, int N, int K) {
    __shared__ short lds_a[128 * 32];
    __shared__ short lds_b[128 * 32];
    const int tid = threadIdx.x;
    const int lane = tid & 63;
    const int wv = tid >> 6;
    const int m0 = blockIdx.y * 128;
    const int n0 = blockIdx.x * 128;
    const int wm = (wv >> 1) * 64;
    const int wn = (wv & 1) * 64;

    f32x4 acc[4][4];
    #pragma unroll
    for (int i = 0; i < 4; i++)
        #pragma unroll
        for (int j = 0; j < 4; j++) { acc[i][j][0]=0.f; acc[i][j][1]=0.f; acc[i][j][2]=0.f; acc[i][j][3]=0.f; }

    // staging: thread tid loads 16B: row = tid>>2 (plus +64 for 2nd chunk), k-part (tid&3)*8
    // LDS dest = tid*8 shorts -> lane-contiguous (global_load_lds requirement; no padding)
    const int srow = tid >> 2;
    const int sk = (tid & 3) * 8;
    const short* Aa = A + (long)(m0 + srow) * K + sk;      // rows >= M read garbage; rows not stored
    const short* Bb = Bt + (long)(n0 + srow) * K + sk;
    short* la = lds_a + tid * 8;
    short* lb = lds_b + tid * 8;

    const int quad = lane >> 4;
    const int l15 = lane & 15;
    const short* ra = lds_a + (wm + l15) * 32 + quad * 8;
    const short* rb = lds_b + (wn + l15) * 32 + quad * 8;

    for (int k0 = 0; k0 < K; k0 += 32) {
        __syncthreads();                       // prev tile fully consumed
        gl_lds16(Aa + k0, la);
        gl_lds16(Aa + (long)64 * K + k0, la + 64 * 32);
        gl_lds16(Bb + k0, lb);
        gl_lds16(Bb + (long)64 * K + k0, lb + 64 * 32);
        __syncthreads();                       // vmcnt(0) drain -> tile visible
        short8 af[4], bf[4];
        #pragma unroll
        for (int mt = 0; mt < 4; mt++) af[mt] = *(const short8*)(ra + mt * 16 * 32);
        #pragma unroll
        for (int nt = 0; nt < 4; nt++) bf[nt] = *(const short8*)(rb + nt * 16 * 32);
        #pragma unroll
        for (int mt = 0; mt < 4; mt++)
            #pragma unroll
            for (int nt = 0; nt < 4; nt++)
                acc[mt][nt] = __builtin_amdgcn_mfma_f32_16x16x32_bf16(af[mt], bf[nt], acc[mt][nt], 0, 0, 0);
    }

    #pragma unroll
    for (int mt = 0; mt < 4; mt++) {
        int rbase = m0 + wm + mt * 16 + quad * 4;
        #pragma unroll
        for (int nt = 0; nt < 4; nt++) {
            int col = n0 + wn + nt * 16 + l15;
            float bv = bias[col];
            #pragma unroll
            for (int r = 0; r < 4; r++) {
                int row = rbase + r;
                if (row < M) {
                    float v = acc[mt][nt][r] + bv;
                    if (GELU_ACT) v = 0.5f * v * (1.0f + erff(v * 0.70710678118654752f));
                    if (HAS_RES) v += Res[(long)row * N + col];
                    if (OUT_BF16) ((unsigned short*)Cout)[(long)row * N + col] = f2bf(v);
                    else          ((float*)Cout)[(long)row * N + col] = v;
                }
            }
        }
    }
}

// ---------------- windowed attention: wave = (window, head); f32 K/V staged in LDS ------
__global__ __launch_bounds__(256) void winattn_kernel(const short* __restrict__ qkv,
                                                      const float* __restrict__ bias_exp,
                                                      const float* __restrict__ xin,
                                                      float* __restrict__ XALL) {
    // per-wave LDS: 37 rows x (32 K-floats | 32 V-floats) = 9472 B; x4 waves = 37888 B
    __shared__ float kvs[4][37 * 64];
    const int tid = threadIdx.x;
    const int wv = tid >> 6;
    const int lane = tid & 63;
    const int gw = blockIdx.x * 4 + wv;            // global wave = (win, head)
    const int win = gw >> 4;
    const int h = gw & 15;
    const int b = win >> 6;
    const int i1 = (win >> 3) & 7;
    const int i3 = win & 7;

    float* lws = kvs[wv];

    // stage this head's K and V slices, converting bf16->f32 ONCE here
    // c in [0, 296): c<148 => K, else V; 4 chunks of 8 elements per row
    for (int c = lane; c < 296; c += 64) {
        int cc = c;
        int voff = 512;          // K columns
        int doff = 0;
        if (cc >= 148) { cc -= 148; voff = 1024; doff = 32; }
        int row = cc >> 2;
        int part = cc & 3;
        int grow;
        if (row < 36) { int i2 = row / 6, i4 = row % 6; grow = b * SEQL + (i1*6 + i2) * 48 + i3*6 + i4; }
        else grow = XROWS + b;
        int4 raw = *(const int4*)(qkv + (long)grow * 1536 + voff + h * 32 + part * 8);
        float tmp[8];
        unpack8(raw, tmp);
        float* dstp = &lws[row * 64 + doff + part * 8];
        *(float4*)dstp       = make_float4(tmp[0], tmp[1], tmp[2], tmp[3]);
        *(float4*)(dstp + 4) = make_float4(tmp[4], tmp[5], tmp[6], tmp[7]);
    }
    __syncthreads();

    const int qi = lane;
    if (qi >= 36) return;
    int i2 = qi / 6, i4 = qi % 6;
    const int growq = b * SEQL + (i1*6 + i2) * 48 + i3*6 + i4;

    // load Q row (this head), pre-scale
    float qr[32];
    {
        const int4* qp = (const int4*)(qkv + (long)growq * 1536 + h * 32);
        unpack8(qp[0], qr); unpack8(qp[1], qr + 8); unpack8(qp[2], qr + 16); unpack8(qp[3], qr + 24);
        #pragma unroll
        for (int d = 0; d < 32; d++) qr[d] *= ATT_SCALE;
    }

    const float* brow = bias_exp + h * (36*37) + qi * 37;
    float s[37];
    float mx = -1e30f;
    #pragma unroll
    for (int j = 0; j < 37; j++) {
        float kr[32];
        #pragma unroll
        for (int t4 = 0; t4 < 8; t4++) *(float4*)(kr + t4*4) = *(const float4*)(lws + j * 64 + t4 * 4);
        float d0 = 0.f, d1 = 0.f, d2 = 0.f, d3 = 0.f;
        #pragma unroll
        for (int dd = 0; dd < 8; dd++) {
            d0 += qr[dd]      * kr[dd];
            d1 += qr[8 + dd]  * kr[8 + dd];
            d2 += qr[16 + dd] * kr[16 + dd];
            d3 += qr[24 + dd] * kr[24 + dd];
        }
        float sv = (d0 + d1 + d2 + d3) + brow[j];
        s[j] = sv;
        mx = fmaxf(mx, sv);
    }
    float sum = 0.f;
    #pragma unroll
    for (int j = 0; j < 37; j++) { s[j] = __expf(s[j] - mx); sum += s[j]; }
    float inv_sum = 1.0f / sum;

    float o[32];
    #pragma unroll
    for (int dd = 0; dd < 32; dd++) o[dd] = 0.f;
    #pragma unroll
    for (int j = 0; j < 37; j++) {
        float vr[32];
        #pragma unroll
        for (int t4 = 0; t4 < 8; t4++) *(float4*)(vr + t4*4) = *(const float4*)(lws + j * 64 + 32 + t4 * 4);
        float p = s[j];
        #pragma unroll
        for (int dd = 0; dd < 32; dd++) o[dd] += p * vr[dd];
    }

    const float* xi = xin + (long)growq * DIM + h * 32;
    float* xo = XALL + (long)growq * DIM + h * 32;
    #pragma unroll
    for (int v4 = 0; v4 < 8; v4++) {
        float4 xv = *(const float4*)(xi + v4 * 4);
        float4 ov;
        ov.x = xv.x + o[v4*4 + 0] * inv_sum;
        ov.y = xv.y + o[v4*4 + 1] * inv_sum;
        ov.z = xv.z + o[v4*4 + 2] * inv_sum;
        ov.w = xv.w + o[v4*4 + 3] * inv_sum;
        *(float4*)(xo + v4 * 4) = ov;
    }
}

// ---------------- global-token attention: 1 block (256 thr) per (batch, head) -----------
__global__ __launch_bounds__(256) void gattn_kernel(const short* __restrict__ qkv,
                                                    const float* __restrict__ xavg,
                                                    float* __restrict__ XALL) {
    const int b = blockIdx.x >> 4;
    const int h = blockIdx.x & 15;
    const int tid = threadIdx.x;
    __shared__ float qs[32];
    __shared__ float redm[4], redsum[4];
    __shared__ float wout[4][32];
    if (tid < 32) qs[tid] = bf2f(((const unsigned short*)qkv)[(long)(XROWS + b) * 1536 + h * 32 + tid]);
    __syncthreads();
    float qr[32];
    #pragma unroll
    for (int d = 0; d < 32; d++) qr[d] = qs[d];
    float s[9];
    float mx = -1e30f;
    #pragma unroll
    for (int i = 0; i < 9; i++) {
        int t = tid + i * 256;
        const int4* kp = (const int4*)(qkv + (long)(b * SEQL + t) * 1536 + 512 + h * 32);
        float kr[32];
        unpack8(kp[0], kr); unpack8(kp[1], kr + 8); unpack8(kp[2], kr + 16); unpack8(kp[3], kr + 24);
        float d0 = 0.f, d1 = 0.f, d2 = 0.f, d3 = 0.f;
        #pragma unroll
        for (int dd = 0; dd < 8; dd++) {
            d0 += qr[dd] * kr[dd]; d1 += qr[8+dd] * kr[8+dd];
            d2 += qr[16+dd] * kr[16+dd]; d3 += qr[24+dd] * kr[24+dd];
        }
        s[i] = (d0 + d1 + d2 + d3) * ATT_SCALE;
        mx = fmaxf(mx, s[i]);
    }
    for (int m = 1; m < 64; m <<= 1) mx = fmaxf(mx, __shfl_xor(mx, m));
    if ((tid & 63) == 0) redm[tid >> 6] = mx;
    __syncthreads();
    mx = fmaxf(fmaxf(redm[0], redm[1]), fmaxf(redm[2], redm[3]));
    float sum = 0.f;
    #pragma unroll
    for (int i = 0; i < 9; i++) { s[i] = __expf(s[i] - mx); sum += s[i]; }
    for (int m = 1; m < 64; m <<= 1) sum += __shfl_xor(sum, m);
    if ((tid & 63) == 0) redsum[tid >> 6] = sum;
    __syncthreads();
    sum = redsum[0] + redsum[1] + redsum[2] + redsum[3];
    float o[32];
    #pragma unroll
    for (int d = 0; d < 32; d++) o[d] = 0.f;
    #pragma unroll
    for (int i = 0; i < 9; i++) {
        int t = tid + i * 256;
        const int4* vp = (const int4*)(qkv + (long)(b * SEQL + t) * 1536 + 1024 + h * 32);
        float vr[32];
        unpack8(vp[0], vr); unpack8(vp[1], vr + 8); unpack8(vp[2], vr + 16); unpack8(vp[3], vr + 24);
        float p = s[i];
        #pragma unroll
        for (int d = 0; d < 32; d++) o[d] += p * vr[d];
    }
    for (int m = 1; m < 64; m <<= 1) {
        #pragma unroll
        for (int d = 0; d < 32; d++) o[d] += __shfl_xor(o[d], m);
    }
    if ((tid & 63) == 0) {
        #pragma unroll
        for (int d = 0; d < 32; d++) wout[tid >> 6][d] = o[d];
    }
    __syncthreads();
    if (tid < 32) {
        float t = wout[0][tid] + wout[1][tid] + wout[2][tid] + wout[3][tid];
        XALL[(long)(XROWS + b) * DIM + h * 32 + tid] = xavg[b * DIM + h * 32 + tid] + t / sum;
    }
}

// ---------------- launch --------------------------------------------------------------
extern "C" void kernel_launch(void* const* d_in, const int* in_sizes, int n_in,
                              void* d_out, int out_size, void* d_ws, size_t ws_size,
                              hipStream_t stream) {
    const float* x      = (const float*)d_in[0];
    const float* xavg   = (const float*)d_in[1];
    const float* w_kv   = (const float*)d_in[2];
    const float* b_kv   = (const float*)d_in[3];
    const float* w_q    = (const float*)d_in[4];
    const float* b_q    = (const float*)d_in[5];
    const float* rel    = (const float*)d_in[6];
    const float* g1     = (const float*)d_in[7];
    const float* be1    = (const float*)d_in[8];
    const float* g2     = (const float*)d_in[9];
    const float* be2    = (const float*)d_in[10];
    const float* w_fc1  = (const float*)d_in[11];
    const float* b_fc1  = (const float*)d_in[12];
    const float* w_fc2  = (const float*)d_in[13];
    const float* b_fc2  = (const float*)d_in[14];

    char* ws = (char*)d_ws;
    size_t off = 0;
    auto alloc = [&](size_t bytes) { void* p = ws + off; off += (bytes + 255) & ~(size_t)255; return p; };
    short* qkv_h          = (short*)alloc((size_t)NROWS * 2048 * 2);   // qkv (1536 cols), then MLP hidden (2048 cols)
    float* XALL           = (float*)alloc((size_t)NROWS * 512 * 4);    // attn + residual, f32
    short* xn             = (short*)alloc((size_t)NROWS * 512 * 2);    // LN output, bf16 (reused LN1/LN2)
    unsigned short* Wqkv_t = (unsigned short*)alloc((size_t)1536 * 512 * 2);
    unsigned short* Wfc1_t = (unsigned short*)alloc((size_t)2048 * 512 * 2);
    unsigned short* Wfc2_t = (unsigned short*)alloc((size_t)512 * 2048 * 2);
    float* bqkv           = (float*)alloc(1536 * 4);
    float* bias_exp       = (float*)alloc((size_t)NHEAD * 36 * 37 * 4);

    // 1. weight transposes (coalesced, LDS-tiled) + small pack
    tpose_kernel<<<2816, 256, 0, stream>>>(w_q, w_kv, w_fc1, w_fc2,
                                           Wqkv_t, Wfc1_t, Wfc2_t);
    smallpack_kernel<<<(1536 + NHEAD*36*37 + 255) / 256, 256, 0, stream>>>(b_q, b_kv, rel, bqkv, bias_exp);
    // 2. LN1 over x rows then xavg rows -> xn (bf16)
    ln_kernel<<<(NROWS + 3) / 4, 256, 0, stream>>>(x, xavg, XROWS, g1, be1, (unsigned short*)xn, NROWS);
    // 3. QKV GEMM: [36880,512] x [512,1536] -> qkv bf16
    gemm_kernel<false, true, false><<<dim3(1536 / 128, (NROWS + 127) / 128), 256, 0, stream>>>(
        xn, (const short*)Wqkv_t, bqkv, qkv_h, nullptr, NROWS, 1536, 512);
    // 4. windowed attention + residual -> XALL rows [0, 36864)
    winattn_kernel<<<1024 * 16 / 4, 256, 0, stream>>>(qkv_h, bias_exp, x, XALL);
    // 5. global-token attention + residual -> XALL rows [36864, 36880)
    gattn_kernel<<<256, 256, 0, stream>>>(qkv_h, xavg, XALL);
    // 6. LN2 -> xn (bf16)
    ln_kernel<<<(NROWS + 3) / 4, 256, 0, stream>>>(XALL, XALL + (size_t)XROWS * 512, XROWS, g2, be2,
                                                   (unsigned short*)xn, NROWS);
    // 7. FC1 + GELU: [36880,512] x [512,2048] -> hidden bf16 (reuses qkv region)
    gemm_kernel<true, true, false><<<dim3(2048 / 128, (NROWS + 127) / 128), 256, 0, stream>>>(
        xn, (const short*)Wfc1_t, b_fc1, qkv_h, nullptr, NROWS, 2048, 512);
    // 8. FC2 + bias + residual: [36880,2048] x [2048,512] -> d_out f32
    gemm_kernel<false, false, true><<<dim3(512 / 128, (NROWS + 127) / 128), 256, 0, stream>>>(
        qkv_h, (const short*)Wfc2_t, b_fc2, d_out, XALL, NROWS, 512, 2048);
}

// Round 4
// 777.898 us; speedup vs baseline: 1.9819x; 1.0465x over previous
//
#include <hip/hip_runtime.h>
#include <stdint.h>

#define DIM 512
#define NHEAD 16
#define HEADD 32
#define BATCH 16
#define SEQL 2304
#define XROWS (BATCH*SEQL)        // 36864
#define NROWS (XROWS + BATCH)     // 36880
#define ATT_SCALE 0.17677669529663687f

typedef __attribute__((ext_vector_type(8))) short short8;
typedef __attribute__((ext_vector_type(4))) float f32x4;

__device__ __forceinline__ float bf2f(unsigned short v) {
    union { unsigned u; float f; } t; t.u = ((unsigned)v) << 16; return t.f;
}
__device__ __forceinline__ unsigned short f2bf(float f) {
    union { float f; unsigned u; } t; t.f = f;
    unsigned r = t.u + 0x7fffu + ((t.u >> 16) & 1u);
    return (unsigned short)(r >> 16);
}
__device__ __forceinline__ void unpack8(const int4 c, float* o) {
    union { unsigned u; float f; } t;
    unsigned w0 = (unsigned)c.x, w1 = (unsigned)c.y, w2 = (unsigned)c.z, w3 = (unsigned)c.w;
    t.u = w0 << 16;         o[0] = t.f;
    t.u = w0 & 0xffff0000u; o[1] = t.f;
    t.u = w1 << 16;         o[2] = t.f;
    t.u = w1 & 0xffff0000u; o[3] = t.f;
    t.u = w2 << 16;         o[4] = t.f;
    t.u = w2 & 0xffff0000u; o[5] = t.f;
    t.u = w3 << 16;         o[6] = t.f;
    t.u = w3 & 0xffff0000u; o[7] = t.f;
}
__device__ __forceinline__ void gl_lds16(const void* g, void* l) {
    __builtin_amdgcn_global_load_lds((const __attribute__((address_space(1))) unsigned int*)g,
                                     (__attribute__((address_space(3))) unsigned int*)l,
                                     16, 0, 0);
}

// ---------------- tiled transpose: f32 [Kd][Nd] -> bf16 [Nd][Kd], coalesced both sides --
__global__ __launch_bounds__(256) void tpose_kernel(const float* __restrict__ w_q,
                                                    const float* __restrict__ w_kv,
                                                    const float* __restrict__ w_fc1,
                                                    const float* __restrict__ w_fc2,
                                                    unsigned short* __restrict__ Wqkv_t,
                                                    unsigned short* __restrict__ Wfc1_t,
                                                    unsigned short* __restrict__ Wfc2_t) {
    __shared__ float tile[32][33];
    int t = blockIdx.x;
    const float* src; unsigned short* dst;
    int Kd, Nd, rowOff, tk;
    if (t < 256)        { src = w_q;   dst = Wqkv_t; Kd = 512;  Nd = 512;  rowOff = 0;   tk = 16; }
    else if (t < 768)   { t -= 256;  src = w_kv;  dst = Wqkv_t; Kd = 512;  Nd = 1024; rowOff = 512; tk = 16; }
    else if (t < 1792)  { t -= 768;  src = w_fc1; dst = Wfc1_t; Kd = 512;  Nd = 2048; rowOff = 0;   tk = 16; }
    else                { t -= 1792; src = w_fc2; dst = Wfc2_t; Kd = 2048; Nd = 512;  rowOff = 0;   tk = 64; }
    int k0 = (t % tk) * 32;
    int n0 = (t / tk) * 32;
    int tx = threadIdx.x & 31, ty = threadIdx.x >> 5;
    #pragma unroll
    for (int r = 0; r < 32; r += 8)
        tile[r + ty][tx] = src[(long)(k0 + r + ty) * Nd + n0 + tx];
    __syncthreads();
    #pragma unroll
    for (int r = 0; r < 32; r += 8)
        dst[(long)(rowOff + n0 + r + ty) * Kd + k0 + tx] = f2bf(tile[tx][r + ty]);
}

// ---------------- small pack: qkv bias concat + rel-bias expand -------------------------
__global__ void smallpack_kernel(const float* __restrict__ b_q, const float* __restrict__ b_kv,
                                 const float* __restrict__ rel_table,
                                 float* __restrict__ bqkv, float* __restrict__ bias_exp) {
    int i = blockIdx.x * 256 + threadIdx.x;
    if (i < 1536) { bqkv[i] = (i < 512) ? b_q[i] : b_kv[i - 512]; return; }
    i -= 1536;
    if (i < NHEAD*36*37) {                    // bias_exp[h][qi][j]
        int h = i / (36*37); int rem = i % (36*37); int qi = rem / 37; int j = rem % 37;
        int c0m = qi % 6, c1m = qi / 6;
        int c0n = (j < 36) ? (j % 6) : 0;
        int c1n = (j < 36) ? (j / 6) : 0;
        int id = (c0m - c0n + 5) * 11 + (c1m - c1n + 5);
        bias_exp[i] = rel_table[id * NHEAD + h];
    }
}

// ---------------- LayerNorm: one wave per 512-elem row, bf16 output ---------------------
__global__ __launch_bounds__(256) void ln_kernel(const float* __restrict__ p1,
                                                 const float* __restrict__ p2, int split,
                                                 const float* __restrict__ g, const float* __restrict__ be,
                                                 unsigned short* __restrict__ out, int nrows) {
    int wv = threadIdx.x >> 6, lane = threadIdx.x & 63;
    int r = blockIdx.x * 4 + wv;
    if (r >= nrows) return;
    const float* src = (r < split) ? (p1 + (long)r * DIM) : (p2 + (long)(r - split) * DIM);
    int c0 = lane * 8;
    float4 v0 = *(const float4*)(src + c0);
    float4 v1 = *(const float4*)(src + c0 + 4);
    float s = v0.x+v0.y+v0.z+v0.w + v1.x+v1.y+v1.z+v1.w;
    float q = v0.x*v0.x+v0.y*v0.y+v0.z*v0.z+v0.w*v0.w + v1.x*v1.x+v1.y*v1.y+v1.z*v1.z+v1.w*v1.w;
    for (int m = 1; m < 64; m <<= 1) { s += __shfl_xor(s, m); q += __shfl_xor(q, m); }
    float mean = s * (1.0f/512.0f);
    float var  = q * (1.0f/512.0f) - mean*mean;
    float rs = rsqrtf(var + 1e-3f);
    float4 g0 = *(const float4*)(g + c0);
    float4 g1 = *(const float4*)(g + c0 + 4);
    float4 b0 = *(const float4*)(be + c0);
    float4 b1 = *(const float4*)(be + c0 + 4);
    unsigned short o[8];
    o[0] = f2bf((v0.x-mean)*rs*g0.x + b0.x);
    o[1] = f2bf((v0.y-mean)*rs*g0.y + b0.y);
    o[2] = f2bf((v0.z-mean)*rs*g0.z + b0.z);
    o[3] = f2bf((v0.w-mean)*rs*g0.w + b0.w);
    o[4] = f2bf((v1.x-mean)*rs*g1.x + b1.x);
    o[5] = f2bf((v1.y-mean)*rs*g1.y + b1.y);
    o[6] = f2bf((v1.z-mean)*rs*g1.z + b1.z);
    o[7] = f2bf((v1.w-mean)*rs*g1.w + b1.w);
    *(int4*)(out + (long)r * DIM + c0) = *(const int4*)o;
}

// ---------------- bf16 MFMA GEMM: m97 staging + XOR-swizzled LDS + BK=64 ----------------
// C[M][N] = A[M][K] * Bt[N][K]^T (+bias, opt GELU / residual). 128x128 tile.
// LDS layout: row-major 128 x 8 slots of 16B; physical slot = logical ^ (row & 7).
// Staging lane fetches the global chunk that belongs at its fixed LDS slot; fragment
// ds_read_b128 then hits each bank exactly 2x (free).
template<bool GELU_ACT, bool OUT_BF16, bool HAS_RES>
__global__ __launch_bounds__(256) void gemm_kernel(const short* __restrict__ A,
                                                   const short* __restrict__ Bt,
                                                   const float* __restrict__ bias,
                                                   void* __restrict__ Cout,
                                                   const float* __restrict__ Res,
                                                   int M, int N, int K) {
    __shared__ short lds_a[128 * 64];
    __shared__ short lds_b[128 * 64];
    const int tid = threadIdx.x;
    const int lane = tid & 63;
    const int wv = tid >> 6;
    const int m0 = blockIdx.y * 128;
    const int n0 = blockIdx.x * 128;
    const int wm = (wv >> 1) * 64;
    const int wn = (wv & 1) * 64;

    f32x4 acc[4][4];
    #pragma unroll
    for (int i = 0; i < 4; i++)
        #pragma unroll
        for (int j = 0; j < 4; j++) { acc[i][j][0]=0.f; acc[i][j][1]=0.f; acc[i][j][2]=0.f; acc[i][j][3]=0.f; }

    // staging: LDS chunk index = i*256 + tid  ->  row = i*32 + (tid>>3), slot = tid & 7
    // global k-slot for (row, slot): slot ^ (row & 7)
    const int srow = tid >> 3;                 // 0..31
    const int ssl  = tid & 7;
    const int msl  = ssl ^ (srow & 7);         // (i*32) % 8 == 0 so row&7 == srow&7
    const short* Aa = A + (long)(m0 + srow) * K + msl * 8;
    const short* Bb = Bt + (long)(n0 + srow) * K + msl * 8;
    short* la = lds_a + tid * 8;
    short* lb = lds_b + tid * 8;

    const int quad = lane >> 4;
    const int l15 = lane & 15;
    // fragment read: logical slot = s*4 + quad, physical = logical ^ (l15 & 7)
    const short* ra0 = lds_a + (wm + l15) * 64 + ((quad)     ^ (l15 & 7)) * 8;
    const short* ra1 = lds_a + (wm + l15) * 64 + ((4 + quad) ^ (l15 & 7)) * 8;
    const short* rb0 = lds_b + (wn + l15) * 64 + ((quad)     ^ (l15 & 7)) * 8;
    const short* rb1 = lds_b + (wn + l15) * 64 + ((4 + quad) ^ (l15 & 7)) * 8;

    for (int k0 = 0; k0 < K; k0 += 64) {
        __syncthreads();                       // prev tile fully consumed
        #pragma unroll
        for (int i = 0; i < 4; i++) {
            gl_lds16(Aa + (long)(i * 32) * K + k0, la + i * 256 * 8);
            gl_lds16(Bb + (long)(i * 32) * K + k0, lb + i * 256 * 8);
        }
        __syncthreads();                       // vmcnt(0) drain -> tile visible
        short8 af[4], bf[4];
        // sub-step 0: k = k0..k0+31
        #pragma unroll
        for (int mt = 0; mt < 4; mt++) af[mt] = *(const short8*)(ra0 + mt * 16 * 64);
        #pragma unroll
        for (int nt = 0; nt < 4; nt++) bf[nt] = *(const short8*)(rb0 + nt * 16 * 64);
        #pragma unroll
        for (int mt = 0; mt < 4; mt++)
            #pragma unroll
            for (int nt = 0; nt < 4; nt++)
                acc[mt][nt] = __builtin_amdgcn_mfma_f32_16x16x32_bf16(af[mt], bf[nt], acc[mt][nt], 0, 0, 0);
        // sub-step 1: k = k0+32..k0+63
        #pragma unroll
        for (int mt = 0; mt < 4; mt++) af[mt] = *(const short8*)(ra1 + mt * 16 * 64);
        #pragma unroll
        for (int nt = 0; nt < 4; nt++) bf[nt] = *(const short8*)(rb1 + nt * 16 * 64);
        #pragma unroll
        for (int mt = 0; mt < 4; mt++)
            #pragma unroll
            for (int nt = 0; nt < 4; nt++)
                acc[mt][nt] = __builtin_amdgcn_mfma_f32_16x16x32_bf16(af[mt], bf[nt], acc[mt][nt], 0, 0, 0);
    }

    #pragma unroll
    for (int mt = 0; mt < 4; mt++) {
        int rbase = m0 + wm + mt * 16 + quad * 4;
        #pragma unroll
        for (int nt = 0; nt < 4; nt++) {
            int col = n0 + wn + nt * 16 + l15;
            float bv = bias[col];
            #pragma unroll
            for (int r = 0; r < 4; r++) {
                int row = rbase + r;
                if (row < M) {
                    float v = acc[mt][nt][r] + bv;
                    if (GELU_ACT) v = 0.5f * v * (1.0f + erff(v * 0.70710678118654752f));
                    if (HAS_RES) v += Res[(long)row * N + col];
                    if (OUT_BF16) ((unsigned short*)Cout)[(long)row * N + col] = f2bf(v);
                    else          ((float*)Cout)[(long)row * N + col] = v;
                }
            }
        }
    }
}

// ---------------- windowed attention: wave = (window, head); f32 K/V staged in LDS ------
__global__ __launch_bounds__(256) void winattn_kernel(const short* __restrict__ qkv,
                                                      const float* __restrict__ bias_exp,
                                                      const float* __restrict__ xin,
                                                      float* __restrict__ XALL) {
    // per-wave LDS: 37 rows x (32 K-floats | 32 V-floats) = 9472 B; x4 waves = 37888 B
    __shared__ float kvs[4][37 * 64];
    const int tid = threadIdx.x;
    const int wv = tid >> 6;
    const int lane = tid & 63;
    const int gw = blockIdx.x * 4 + wv;            // global wave = (win, head)
    const int win = gw >> 4;
    const int h = gw & 15;
    const int b = win >> 6;
    const int i1 = (win >> 3) & 7;
    const int i3 = win & 7;

    float* lws = kvs[wv];

    // stage this head's K and V slices, converting bf16->f32 ONCE here
    for (int c = lane; c < 296; c += 64) {
        int cc = c;
        int voff = 512;          // K columns
        int doff = 0;
        if (cc >= 148) { cc -= 148; voff = 1024; doff = 32; }
        int row = cc >> 2;
        int part = cc & 3;
        int grow;
        if (row < 36) { int i2 = row / 6, i4 = row % 6; grow = b * SEQL + (i1*6 + i2) * 48 + i3*6 + i4; }
        else grow = XROWS + b;
        int4 raw = *(const int4*)(qkv + (long)grow * 1536 + voff + h * 32 + part * 8);
        float tmp[8];
        unpack8(raw, tmp);
        float* dstp = &lws[row * 64 + doff + part * 8];
        *(float4*)dstp       = make_float4(tmp[0], tmp[1], tmp[2], tmp[3]);
        *(float4*)(dstp + 4) = make_float4(tmp[4], tmp[5], tmp[6], tmp[7]);
    }
    __syncthreads();

    const int qi = lane;
    if (qi >= 36) return;
    int i2 = qi / 6, i4 = qi % 6;
    const int growq = b * SEQL + (i1*6 + i2) * 48 + i3*6 + i4;

    // load Q row (this head), pre-scale
    float qr[32];
    {
        const int4* qp = (const int4*)(qkv + (long)growq * 1536 + h * 32);
        unpack8(qp[0], qr); unpack8(qp[1], qr + 8); unpack8(qp[2], qr + 16); unpack8(qp[3], qr + 24);
        #pragma unroll
        for (int d = 0; d < 32; d++) qr[d] *= ATT_SCALE;
    }

    const float* brow = bias_exp + h * (36*37) + qi * 37;
    float s[37];
    float mx = -1e30f;
    #pragma unroll
    for (int j = 0; j < 37; j++) {
        float kr[32];
        #pragma unroll
        for (int t4 = 0; t4 < 8; t4++) *(float4*)(kr + t4*4) = *(const float4*)(lws + j * 64 + t4 * 4);
        float d0 = 0.f, d1 = 0.f, d2 = 0.f, d3 = 0.f;
        #pragma unroll
        for (int dd = 0; dd < 8; dd++) {
            d0 += qr[dd]      * kr[dd];
            d1 += qr[8 + dd]  * kr[8 + dd];
            d2 += qr[16 + dd] * kr[16 + dd];
            d3 += qr[24 + dd] * kr[24 + dd];
        }
        float sv = (d0 + d1 + d2 + d3) + brow[j];
        s[j] = sv;
        mx = fmaxf(mx, sv);
    }
    float sum = 0.f;
    #pragma unroll
    for (int j = 0; j < 37; j++) { s[j] = __expf(s[j] - mx); sum += s[j]; }
    float inv_sum = 1.0f / sum;

    float o[32];
    #pragma unroll
    for (int dd = 0; dd < 32; dd++) o[dd] = 0.f;
    #pragma unroll
    for (int j = 0; j < 37; j++) {
        float vr[32];
        #pragma unroll
        for (int t4 = 0; t4 < 8; t4++) *(float4*)(vr + t4*4) = *(const float4*)(lws + j * 64 + 32 + t4 * 4);
        float p = s[j];
        #pragma unroll
        for (int dd = 0; dd < 32; dd++) o[dd] += p * vr[dd];
    }

    const float* xi = xin + (long)growq * DIM + h * 32;
    float* xo = XALL + (long)growq * DIM + h * 32;
    #pragma unroll
    for (int v4 = 0; v4 < 8; v4++) {
        float4 xv = *(const float4*)(xi + v4 * 4);
        float4 ov;
        ov.x = xv.x + o[v4*4 + 0] * inv_sum;
        ov.y = xv.y + o[v4*4 + 1] * inv_sum;
        ov.z = xv.z + o[v4*4 + 2] * inv_sum;
        ov.w = xv.w + o[v4*4 + 3] * inv_sum;
        *(float4*)(xo + v4 * 4) = ov;
    }
}

// ---------------- global-token attention: 1 block (256 thr) per (batch, head) -----------
__global__ __launch_bounds__(256) void gattn_kernel(const short* __restrict__ qkv,
                                                    const float* __restrict__ xavg,
                                                    float* __restrict__ XALL) {
    const int b = blockIdx.x >> 4;
    const int h = blockIdx.x & 15;
    const int tid = threadIdx.x;
    __shared__ float qs[32];
    __shared__ float redm[4], redsum[4];
    __shared__ float wout[4][32];
    if (tid < 32) qs[tid] = bf2f(((const unsigned short*)qkv)[(long)(XROWS + b) * 1536 + h * 32 + tid]);
    __syncthreads();
    float qr[32];
    #pragma unroll
    for (int d = 0; d < 32; d++) qr[d] = qs[d];
    float s[9];
    float mx = -1e30f;
    #pragma unroll
    for (int i = 0; i < 9; i++) {
        int t = tid + i * 256;
        const int4* kp = (const int4*)(qkv + (long)(b * SEQL + t) * 1536 + 512 + h * 32);
        float kr[32];
        unpack8(kp[0], kr); unpack8(kp[1], kr + 8); unpack8(kp[2], kr + 16); unpack8(kp[3], kr + 24);
        float d0 = 0.f, d1 = 0.f, d2 = 0.f, d3 = 0.f;
        #pragma unroll
        for (int dd = 0; dd < 8; dd++) {
            d0 += qr[dd] * kr[dd]; d1 += qr[8+dd] * kr[8+dd];
            d2 += qr[16+dd] * kr[16+dd]; d3 += qr[24+dd] * kr[24+dd];
        }
        s[i] = (d0 + d1 + d2 + d3) * ATT_SCALE;
        mx = fmaxf(mx, s[i]);
    }
    for (int m = 1; m < 64; m <<= 1) mx = fmaxf(mx, __shfl_xor(mx, m));
    if ((tid & 63) == 0) redm[tid >> 6] = mx;
    __syncthreads();
    mx = fmaxf(fmaxf(redm[0], redm[1]), fmaxf(redm[2], redm[3]));
    float sum = 0.f;
    #pragma unroll
    for (int i = 0; i < 9; i++) { s[i] = __expf(s[i] - mx); sum += s[i]; }
    for (int m = 1; m < 64; m <<= 1) sum += __shfl_xor(sum, m);
    if ((tid & 63) == 0) redsum[tid >> 6] = sum;
    __syncthreads();
    sum = redsum[0] + redsum[1] + redsum[2] + redsum[3];
    float o[32];
    #pragma unroll
    for (int d = 0; d < 32; d++) o[d] = 0.f;
    #pragma unroll
    for (int i = 0; i < 9; i++) {
        int t = tid + i * 256;
        const int4* vp = (const int4*)(qkv + (long)(b * SEQL + t) * 1536 + 1024 + h * 32);
        float vr[32];
        unpack8(vp[0], vr); unpack8(vp[1], vr + 8); unpack8(vp[2], vr + 16); unpack8(vp[3], vr + 24);
        float p = s[i];
        #pragma unroll
        for (int d = 0; d < 32; d++) o[d] += p * vr[d];
    }
    for (int m = 1; m < 64; m <<= 1) {
        #pragma unroll
        for (int d = 0; d < 32; d++) o[d] += __shfl_xor(o[d], m);
    }
    if ((tid & 63) == 0) {
        #pragma unroll
        for (int d = 0; d < 32; d++) wout[tid >> 6][d] = o[d];
    }
    __syncthreads();
    if (tid < 32) {
        float t = wout[0][tid] + wout[1][tid] + wout[2][tid] + wout[3][tid];
        XALL[(long)(XROWS + b) * DIM + h * 32 + tid] = xavg[b * DIM + h * 32 + tid] + t / sum;
    }
}

// ---------------- launch --------------------------------------------------------------
extern "C" void kernel_launch(void* const* d_in, const int* in_sizes, int n_in,
                              void* d_out, int out_size, void* d_ws, size_t ws_size,
                              hipStream_t stream) {
    const float* x      = (const float*)d_in[0];
    const float* xavg   = (const float*)d_in[1];
    const float* w_kv   = (const float*)d_in[2];
    const float* b_kv   = (const float*)d_in[3];
    const float* w_q    = (const float*)d_in[4];
    const float* b_q    = (const float*)d_in[5];
    const float* rel    = (const float*)d_in[6];
    const float* g1     = (const float*)d_in[7];
    const float* be1    = (const float*)d_in[8];
    const float* g2     = (const float*)d_in[9];
    const float* be2    = (const float*)d_in[10];
    const float* w_fc1  = (const float*)d_in[11];
    const float* b_fc1  = (const float*)d_in[12];
    const float* w_fc2  = (const float*)d_in[13];
    const float* b_fc2  = (const float*)d_in[14];

    char* ws = (char*)d_ws;
    size_t off = 0;
    auto alloc = [&](size_t bytes) { void* p = ws + off; off += (bytes + 255) & ~(size_t)255; return p; };
    short* qkv_h          = (short*)alloc((size_t)NROWS * 2048 * 2);   // qkv (1536 cols), then MLP hidden (2048 cols)
    float* XALL           = (float*)alloc((size_t)NROWS * 512 * 4);    // attn + residual, f32
    short* xn             = (short*)alloc((size_t)NROWS * 512 * 2);    // LN output, bf16 (reused LN1/LN2)
    unsigned short* Wqkv_t = (unsigned short*)alloc((size_t)1536 * 512 * 2);
    unsigned short* Wfc1_t = (unsigned short*)alloc((size_t)2048 * 512 * 2);
    unsigned short* Wfc2_t = (unsigned short*)alloc((size_t)512 * 2048 * 2);
    float* bqkv           = (float*)alloc(1536 * 4);
    float* bias_exp       = (float*)alloc((size_t)NHEAD * 36 * 37 * 4);

    // 1. weight transposes (coalesced, LDS-tiled) + small pack
    tpose_kernel<<<2816, 256, 0, stream>>>(w_q, w_kv, w_fc1, w_fc2,
                                           Wqkv_t, Wfc1_t, Wfc2_t);
    smallpack_kernel<<<(1536 + NHEAD*36*37 + 255) / 256, 256, 0, stream>>>(b_q, b_kv, rel, bqkv, bias_exp);
    // 2. LN1 over x rows then xavg rows -> xn (bf16)
    ln_kernel<<<(NROWS + 3) / 4, 256, 0, stream>>>(x, xavg, XROWS, g1, be1, (unsigned short*)xn, NROWS);
    // 3. QKV GEMM: [36880,512] x [512,1536] -> qkv bf16
    gemm_kernel<false, true, false><<<dim3(1536 / 128, (NROWS + 127) / 128), 256, 0, stream>>>(
        xn, (const short*)Wqkv_t, bqkv, qkv_h, nullptr, NROWS, 1536, 512);
    // 4. windowed attention + residual -> XALL rows [0, 36864)
    winattn_kernel<<<1024 * 16 / 4, 256, 0, stream>>>(qkv_h, bias_exp, x, XALL);
    // 5. global-token attention + residual -> XALL rows [36864, 36880)
    gattn_kernel<<<256, 256, 0, stream>>>(qkv_h, xavg, XALL);
    // 6. LN2 -> xn (bf16)
    ln_kernel<<<(NROWS + 3) / 4, 256, 0, stream>>>(XALL, XALL + (size_t)XROWS * 512, XROWS, g2, be2,
                                                   (unsigned short*)xn, NROWS);
    // 7. FC1 + GELU: [36880,512] x [512,2048] -> hidden bf16 (reuses qkv region)
    gemm_kernel<true, true, false><<<dim3(2048 / 128, (NROWS + 127) / 128), 256, 0, stream>>>(
        xn, (const short*)Wfc1_t, b_fc1, qkv_h, nullptr, NROWS, 2048, 512);
    // 8. FC2 + bias + residual: [36880,2048] x [2048,512] -> d_out f32
    gemm_kernel<false, false, true><<<dim3(512 / 128, (NROWS + 127) / 128), 256, 0, stream>>>(
        qkv_h, (const short*)Wfc2_t, b_fc2, d_out, XALL, NROWS, 512, 2048);
}